// Round 5
// baseline (307.762 us; speedup 1.0000x reference)
//
#include <hip/hip_runtime.h>
#include <hip/hip_bf16.h>
#include <stdint.h>

// Problem constants (fixed by setup_inputs)
#define NE   8
#define DOUT 2048
#define DIN  2048
#define SEQ  8192
#define GSZ  128
#define FP8_MAX 448.0f
#define EPSQ 1e-12f

typedef float f32x4  __attribute__((ext_vector_type(4)));
typedef float f32x16 __attribute__((ext_vector_type(16)));
typedef int   i32x4  __attribute__((ext_vector_type(4)));
typedef int   i32x8  __attribute__((ext_vector_type(8)));

// async global->LDS, 16B/lane. LDS dest = wave-uniform base (+lane*16 by HW);
// global src may be per-lane.
__device__ __forceinline__ void async16(void* lds_base, const void* gptr) {
    __builtin_amdgcn_global_load_lds(
        (const __attribute__((address_space(1))) unsigned int*)gptr,
        (__attribute__((address_space(3))) unsigned int*)lds_base,
        16, 0, 0);
}

// ---------------------------------------------------------------------------
// Kernel 1: per-1x128-tile quant of x. One float4 per thread; each 32-lane
// half-wave group covers one tile. Coalesced float4 loads, dword stores.
__global__ __launch_bounds__(256) void quant_x_kernel(
    const float* __restrict__ x, unsigned char* __restrict__ qx,
    float* __restrict__ sx)
{
    const int g = blockIdx.x * 256 + threadIdx.x;   // float4 group index
    const float4 v = ((const float4*)x)[g];
    float a = fmaxf(fmaxf(fabsf(v.x), fabsf(v.y)),
                    fmaxf(fabsf(v.z), fabsf(v.w)));
    #pragma unroll
    for (int o = 16; o; o >>= 1) a = fmaxf(a, __shfl_xor(a, o));  // 32-lane tile
    const float scale = fmaxf(a, EPSQ) / FP8_MAX;
    const int tile = g >> 5;                        // == row*16 + kb
    if ((threadIdx.x & 31) == 0) sx[tile] = scale;

    float q0 = fminf(fmaxf(v.x / scale, -FP8_MAX), FP8_MAX);
    float q1 = fminf(fmaxf(v.y / scale, -FP8_MAX), FP8_MAX);
    float q2 = fminf(fmaxf(v.z / scale, -FP8_MAX), FP8_MAX);
    float q3 = fminf(fmaxf(v.w / scale, -FP8_MAX), FP8_MAX);
    int lo = __builtin_amdgcn_cvt_pk_fp8_f32(q0, q1, 0, false);
    int pk = __builtin_amdgcn_cvt_pk_fp8_f32(q2, q3, lo, true);
    ((unsigned int*)qx)[g] = (unsigned int)pk;
}

// ---------------------------------------------------------------------------
// Kernel 2: per-128x128-block quant of w. Stage block into 64 KB LDS via
// global_load_lds, amax from LDS, quantize from LDS.
__global__ __launch_bounds__(256) void quant_w_kernel(
    const float* __restrict__ w, unsigned char* __restrict__ qw,
    float* __restrict__ sw)
{
    __shared__ float buf[128 * 128];   // 64 KB
    __shared__ float red[4];

    const int cb = blockIdx.x;   // din block 0..15
    const int rb = blockIdx.y;   // dout block 0..15
    const int e  = blockIdx.z;   // expert 0..7
    const int t  = threadIdx.x;
    const int lane = t & 63, wv = t >> 6;

    const size_t base = ((size_t)e * DOUT + rb * GSZ) * DIN + cb * GSZ;
    const float* wp = w + base;

    // stage 64 KB: 4 waves x 16 iters x 1 KB. 32 sixteen-byte chunks per row.
    #pragma unroll
    for (int j = 0; j < 16; ++j) {
        int f16 = (wv * 16 + j) * 64 + lane;     // 16-byte chunk index 0..4095
        int row = f16 >> 5, cc = f16 & 31;
        async16(buf + (wv * 16 + j) * 256,
                wp + (size_t)row * DIN + cc * 4);
    }
    __syncthreads();

    float a = 0.f;
    #pragma unroll
    for (int i = 0; i < 16; ++i) {
        f32x4 v = *(const f32x4*)(buf + (t + i * 256) * 4);
        a = fmaxf(a, fmaxf(fmaxf(fabsf(v[0]), fabsf(v[1])),
                           fmaxf(fabsf(v[2]), fabsf(v[3]))));
    }
    #pragma unroll
    for (int o = 32; o; o >>= 1) a = fmaxf(a, __shfl_xor(a, o));
    if (lane == 0) red[wv] = a;
    __syncthreads();
    a = fmaxf(fmaxf(red[0], red[1]), fmaxf(red[2], red[3]));
    const float scale = fmaxf(a, EPSQ) / FP8_MAX;
    if (t == 0) sw[(e * 16 + rb) * 16 + cb] = scale;

    unsigned int* qout = (unsigned int*)(qw + base);
    #pragma unroll
    for (int i = 0; i < 16; ++i) {
        int idx = t + i * 256;
        f32x4 v = *(const f32x4*)(buf + idx * 4);
        float q0 = fminf(fmaxf(v[0] / scale, -FP8_MAX), FP8_MAX);
        float q1 = fminf(fmaxf(v[1] / scale, -FP8_MAX), FP8_MAX);
        float q2 = fminf(fmaxf(v[2] / scale, -FP8_MAX), FP8_MAX);
        float q3 = fminf(fmaxf(v[3] / scale, -FP8_MAX), FP8_MAX);
        int lo = __builtin_amdgcn_cvt_pk_fp8_f32(q0, q1, 0, false);
        int pk = __builtin_amdgcn_cvt_pk_fp8_f32(q2, q3, lo, true);
        int r = idx >> 5, c4 = idx & 31;
        qout[r * (DIN / 4) + c4] = (unsigned int)pk;
    }
}

// ---------------------------------------------------------------------------
// Kernel 3: grouped fp8 GEMM, 256x256 tile, double-buffered LDS, counted
// vmcnt, TWO ks-phases per K-step with mid-barrier role split (T3) + setprio
// (T5), MX-scaled MFMA 32x32x64 fp8 (unit e8m0 scales), XCD-contiguous
// block decomposition.
//
// Per K-step kb (cur = kb&1):
//  phase A: stage 4 (A-half, kb+1) -> vmcnt(4) -> barrier ->
//           ds_read A[mi0..3]ks0 + B[ni0,1]ks0 (12xb128) -> setprio 8 MFMA ->
//           barrier
//  phase B: stage 4 (B-half, kb+1) ->
//           ds_read A ks1 + B ks1 (12xb128) -> setprio 8 MFMA ->
//           TAIL-RESCALE acc *= r_{kb+1}  (r_16 := final scale c[.,15]) ->
//           barrier
// Rescale sits AFTER the MFMAs (off the pre-MFMA critical path); epilogue is
// pure stores. Telescoped per-128-k-block rescale, split row x col:
//   c[s,j] = sx[s,j] * sw[e, n128, j]
//   A_j = A_{j-1} * (Rs[j][s]*SwL[nh][j]) + P_j ; out = A_15 * Rs[0][s]*SwL[nh][0]
// 8 waves (2M x 4N): wave = 128x64 out = acc[4][2] f32x16 (128 regs).
// LDS: 2x(A 32K + B 32K) dbuf + Rs 16K + SwL = ~144 KB -> 1 block/CU.
__global__ __launch_bounds__(512, 2) void gemm_kernel(
    const unsigned char* __restrict__ qx, const float* __restrict__ sx,
    const unsigned char* __restrict__ qw, const float* __restrict__ sw,
    const int* __restrict__ tpe, float* __restrict__ out)
{
    __shared__ __align__(16) unsigned char Asm[2][256 * 128];
    __shared__ __align__(16) unsigned char Bsm[2][256 * 128];
    __shared__ __align__(16) float Rs[16 * 256];   // [kb][row], sx-part
    __shared__ __align__(16) float SwL[2 * 16];    // [nh][kb], sw-part

    const int tid  = threadIdx.x;
    const int lane = tid & 63;
    const int wv   = tid >> 6;          // 0..7
    const int wm   = wv >> 2;           // 0..1  (M half)
    const int wn   = wv & 3;            // 0..3  (N quarter)
    const int l31  = lane & 31;
    const int h    = lane >> 5;
    const int nh   = wn >> 1;           // which 128-col half of the 256 N-tile

    // XCD-contiguous decomposition: XCD c gets mb in [4c, 4c+4), all nb.
    const int lid  = blockIdx.x;        // 0..255
    const int xcd  = lid & 7, t8 = lid >> 3;
    const int mbid = xcd * 4 + (t8 >> 3);   // 0..31
    const int nb   = t8 & 7;                // 0..7
    const int r0   = mbid * 256, n0 = nb * 256;

    int e = -1, start = 0;
    #pragma unroll
    for (int i = 0; i < NE; ++i) {
        int end = start + tpe[i];
        if (r0 >= start && r0 < end) e = i;
        start = end;
    }
    if (e < 0) {
        f32x4 z = {0.f, 0.f, 0.f, 0.f};
        for (int i = tid; i < 256 * 64; i += 512) {
            int r = i >> 6, c4 = i & 63;
            *(f32x4*)(out + (size_t)(r0 + r) * DOUT + n0 + c4 * 4) = z;
        }
        return;
    }

    // ---- prologue: scale ratio tables ----
    for (int i = tid; i < 16 * 256; i += 512) {
        int row = i >> 4, kb = i & 15;
        const float* sp = sx + (size_t)(r0 + row) * 16;
        Rs[kb * 256 + row] = (kb == 0) ? sp[15] : sp[kb - 1] / sp[kb];
    }
    if (tid < 32) {
        int nhh = tid >> 4, kb = tid & 15;
        const float* wp = sw + ((e * 16) + (nb * 2 + nhh)) * 16;
        SwL[nhh * 16 + kb] = (kb == 0) ? wp[15] : wp[kb - 1] / wp[kb];
    }

    const unsigned char* Ag = qx + (size_t)r0 * DIN;
    const unsigned char* Bg = qw + (size_t)e * DOUT * DIN + (size_t)n0 * DIN;

    // staging: wave stages 4 KB of A + 4 KB of B per K-step.
    // 16B-chunk XOR swizzle within each 128 B row: pos = chunk ^ (row&7).
    int soff[4], ldst[4];
    #pragma unroll
    for (int j = 0; j < 4; ++j) {
        int f = wv * 4096 + j * 1024 + lane * 16;   // byte index in 32 KB tile
        int row = f >> 7, pc = (f >> 4) & 7;
        soff[j] = row * DIN + ((pc ^ (row & 7)) * 16);  // + kb*128 at use
        ldst[j] = wv * 4096 + j * 1024;
    }

    // fragment read bases (A row = wm*128+mi*32+l31, B row = wn*64+ni*32+l31)
    int abase[4], ax8[4], bbase[2], bx8[2];
    #pragma unroll
    for (int mi = 0; mi < 4; ++mi) {
        int ra = wm * 128 + mi * 32 + l31;
        abase[mi] = ra * 128; ax8[mi] = ra & 7;
    }
    #pragma unroll
    for (int ni = 0; ni < 2; ++ni) {
        int rb = wn * 64 + ni * 32 + l31;
        bbase[ni] = rb * 128; bx8[ni] = rb & 7;
    }

    // stage kb=0 into buffer 0
    #pragma unroll
    for (int j = 0; j < 4; ++j) {
        async16(Asm[0] + ldst[j], Ag + soff[j]);
        async16(Bsm[0] + ldst[j], Bg + soff[j]);
    }
    // own Rs/SwL ds_writes drained before first barrier (all waves do this)
    asm volatile("s_waitcnt lgkmcnt(0)" ::: "memory");

    f32x16 acc[4][2];
    #pragma unroll
    for (int mi = 0; mi < 4; ++mi)
        #pragma unroll
        for (int ni = 0; ni < 2; ++ni)
            #pragma unroll
            for (int q = 0; q < 16; ++q) acc[mi][ni][q] = 0.f;

    for (int kb = 0; kb < 16; ++kb) {
        const unsigned char* Ac = Asm[kb & 1];
        const unsigned char* Bc = Bsm[kb & 1];
        unsigned char* An = Asm[(kb & 1) ^ 1];
        unsigned char* Bn = Bsm[(kb & 1) ^ 1];

        // ================= phase A (ks = 0) =================
        if (kb < 15) {
            #pragma unroll
            for (int j = 0; j < 4; ++j)
                async16(An + ldst[j], Ag + soff[j] + (kb + 1) * GSZ);
            // 8 older loads (this kb's tile) complete; 4 newest stay in flight
            asm volatile("s_waitcnt vmcnt(4)" ::: "memory");
        } else {
            asm volatile("s_waitcnt vmcnt(0)" ::: "memory");
        }
        __builtin_amdgcn_s_barrier();
        asm volatile("" ::: "memory");

        {
            const int c0 = h * 2;            // ks=0 chunk base
            i32x8 Bk[2];
            #pragma unroll
            for (int ni = 0; ni < 2; ++ni) {
                i32x4 lo = *(const i32x4*)(Bc + bbase[ni] + (((c0    ) ^ bx8[ni]) * 16));
                i32x4 hi = *(const i32x4*)(Bc + bbase[ni] + (((c0 + 1) ^ bx8[ni]) * 16));
                #pragma unroll
                for (int q = 0; q < 4; ++q) { Bk[ni][q] = lo[q]; Bk[ni][q + 4] = hi[q]; }
            }
            i32x8 Afr[4];
            #pragma unroll
            for (int mi = 0; mi < 4; ++mi) {
                i32x4 lo = *(const i32x4*)(Ac + abase[mi] + (((c0    ) ^ ax8[mi]) * 16));
                i32x4 hi = *(const i32x4*)(Ac + abase[mi] + (((c0 + 1) ^ ax8[mi]) * 16));
                #pragma unroll
                for (int q = 0; q < 4; ++q) { Afr[mi][q] = lo[q]; Afr[mi][q + 4] = hi[q]; }
            }
            __builtin_amdgcn_s_setprio(1);
            #pragma unroll
            for (int mi = 0; mi < 4; ++mi)
                #pragma unroll
                for (int ni = 0; ni < 2; ++ni)
                    acc[mi][ni] = __builtin_amdgcn_mfma_scale_f32_32x32x64_f8f6f4(
                        Afr[mi], Bk[ni], acc[mi][ni],
                        0, 0, 0, 0x7f7f7f7f, 0, 0x7f7f7f7f);
            __builtin_amdgcn_s_setprio(0);
        }
        asm volatile("" ::: "memory");
        __builtin_amdgcn_s_barrier();    // mid-phase role-split barrier
        asm volatile("" ::: "memory");

        // ================= phase B (ks = 1) =================
        if (kb < 15) {
            #pragma unroll
            for (int j = 0; j < 4; ++j)
                async16(Bn + ldst[j], Bg + soff[j] + (kb + 1) * GSZ);
        }
        {
            const int c0 = 4 + h * 2;        // ks=1 chunk base
            i32x8 Bk[2];
            #pragma unroll
            for (int ni = 0; ni < 2; ++ni) {
                i32x4 lo = *(const i32x4*)(Bc + bbase[ni] + (((c0    ) ^ bx8[ni]) * 16));
                i32x4 hi = *(const i32x4*)(Bc + bbase[ni] + (((c0 + 1) ^ bx8[ni]) * 16));
                #pragma unroll
                for (int q = 0; q < 4; ++q) { Bk[ni][q] = lo[q]; Bk[ni][q + 4] = hi[q]; }
            }
            i32x8 Afr[4];
            #pragma unroll
            for (int mi = 0; mi < 4; ++mi) {
                i32x4 lo = *(const i32x4*)(Ac + abase[mi] + (((c0    ) ^ ax8[mi]) * 16));
                i32x4 hi = *(const i32x4*)(Ac + abase[mi] + (((c0 + 1) ^ ax8[mi]) * 16));
                #pragma unroll
                for (int q = 0; q < 4; ++q) { Afr[mi][q] = lo[q]; Afr[mi][q + 4] = hi[q]; }
            }
            __builtin_amdgcn_s_setprio(1);
            #pragma unroll
            for (int mi = 0; mi < 4; ++mi)
                #pragma unroll
                for (int ni = 0; ni < 2; ++ni)
                    acc[mi][ni] = __builtin_amdgcn_mfma_scale_f32_32x32x64_f8f6f4(
                        Afr[mi], Bk[ni], acc[mi][ni],
                        0, 0, 0, 0x7f7f7f7f, 0, 0x7f7f7f7f);
            __builtin_amdgcn_s_setprio(0);
        }

        // ---- tail rescale: acc *= r_{kb+1}  (kb=15 -> final scale c[.,15]) ----
        {
            const int kk = (kb < 15) ? kb + 1 : 0;
            const float rwk = SwL[nh * 16 + kk];
            #pragma unroll
            for (int mi = 0; mi < 4; ++mi) {
                const float* rp = Rs + kk * 256 + wm * 128 + mi * 32 + 4 * h;
                f32x4 rr[4];
                #pragma unroll
                for (int g = 0; g < 4; ++g) {
                    f32x4 t = *(const f32x4*)(rp + 8 * g);
                    rr[g] = t * rwk;
                }
                #pragma unroll
                for (int ni = 0; ni < 2; ++ni)
                    #pragma unroll
                    for (int g = 0; g < 4; ++g)
                        #pragma unroll
                        for (int j = 0; j < 4; ++j)
                            acc[mi][ni][g * 4 + j] *= rr[g][j];
            }
        }
        asm volatile("" ::: "memory");
        __builtin_amdgcn_s_barrier();    // buffer-reuse protection
        asm volatile("" ::: "memory");
    }

    // epilogue: pure stores (final scale already applied at kb=15 tail).
    // C/D: col = l31, row = (reg&3) + 8*(reg>>2) + 4*h
    #pragma unroll
    for (int mi = 0; mi < 4; ++mi) {
        const int rbase = r0 + wm * 128 + mi * 32 + 4 * h;
        #pragma unroll
        for (int ni = 0; ni < 2; ++ni) {
            const int col = n0 + wn * 64 + ni * 32 + l31;
            #pragma unroll
            for (int g = 0; g < 4; ++g)
                #pragma unroll
                for (int j = 0; j < 4; ++j)
                    out[(size_t)(rbase + 8 * g + j) * DOUT + col] =
                        acc[mi][ni][g * 4 + j];
        }
    }
}

// ---------------------------------------------------------------------------
extern "C" void kernel_launch(void* const* d_in, const int* in_sizes, int n_in,
                              void* d_out, int out_size, void* d_ws, size_t ws_size,
                              hipStream_t stream) {
    const float* x   = (const float*)d_in[0];   // [8192, 2048] fp32
    const float* wt  = (const float*)d_in[1];   // [16384, 2048] fp32
    const int*   tpe = (const int*)d_in[2];     // [8]
    float* out = (float*)d_out;                 // [8192, 2048] fp32

    char* ws = (char*)d_ws;
    unsigned char* qx = (unsigned char*)ws;                       // 16 MB
    unsigned char* qw = qx + (size_t)SEQ * DIN;                   // 32 MB
    float* sx = (float*)(qw + (size_t)NE * DOUT * DIN);           // 512 KB
    float* sw = sx + (size_t)SEQ * 16;                            // 4 KB

    quant_x_kernel<<<SEQ * DIN / 4 / 256, 256, 0, stream>>>(x, qx, sx);
    quant_w_kernel<<<dim3(16, 16, NE), 256, 0, stream>>>(wt, qw, sw);
    gemm_kernel<<<256, 512, 0, stream>>>(qx, sx, qw, sw, tpe, out);
}

// Round 6
// 297.428 us; speedup vs baseline: 1.0347x; 1.0347x over previous
//
#include <hip/hip_runtime.h>
#include <hip/hip_bf16.h>
#include <stdint.h>

// Problem constants (fixed by setup_inputs)
#define NE   8
#define DOUT 2048
#define DIN  2048
#define SEQ  8192
#define GSZ  128
#define FP8_MAX 448.0f
#define EPSQ 1e-12f

typedef float f32x4  __attribute__((ext_vector_type(4)));
typedef float f32x16 __attribute__((ext_vector_type(16)));
typedef int   i32x4  __attribute__((ext_vector_type(4)));
typedef int   i32x8  __attribute__((ext_vector_type(8)));

// async global->LDS, 16B/lane. LDS dest = wave-uniform base (+lane*16 by HW);
// global src may be per-lane.
__device__ __forceinline__ void async16(void* lds_base, const void* gptr) {
    __builtin_amdgcn_global_load_lds(
        (const __attribute__((address_space(1))) unsigned int*)gptr,
        (__attribute__((address_space(3))) unsigned int*)lds_base,
        16, 0, 0);
}

// ---------------------------------------------------------------------------
// Kernel 1: per-1x128-tile quant of x. One float4 per thread; each 32-lane
// half-wave group covers one tile. Coalesced float4 loads, dword stores.
__global__ __launch_bounds__(256) void quant_x_kernel(
    const float* __restrict__ x, unsigned char* __restrict__ qx,
    float* __restrict__ sx)
{
    const int g = blockIdx.x * 256 + threadIdx.x;   // float4 group index
    const float4 v = ((const float4*)x)[g];
    float a = fmaxf(fmaxf(fabsf(v.x), fabsf(v.y)),
                    fmaxf(fabsf(v.z), fabsf(v.w)));
    #pragma unroll
    for (int o = 16; o; o >>= 1) a = fmaxf(a, __shfl_xor(a, o));  // 32-lane tile
    const float scale = fmaxf(a, EPSQ) / FP8_MAX;
    const int tile = g >> 5;                        // == row*16 + kb
    if ((threadIdx.x & 31) == 0) sx[tile] = scale;

    float q0 = fminf(fmaxf(v.x / scale, -FP8_MAX), FP8_MAX);
    float q1 = fminf(fmaxf(v.y / scale, -FP8_MAX), FP8_MAX);
    float q2 = fminf(fmaxf(v.z / scale, -FP8_MAX), FP8_MAX);
    float q3 = fminf(fmaxf(v.w / scale, -FP8_MAX), FP8_MAX);
    int lo = __builtin_amdgcn_cvt_pk_fp8_f32(q0, q1, 0, false);
    int pk = __builtin_amdgcn_cvt_pk_fp8_f32(q2, q3, lo, true);
    ((unsigned int*)qx)[g] = (unsigned int)pk;
}

// ---------------------------------------------------------------------------
// Kernel 2: per-128x128-block quant of w. Stage block into 64 KB LDS via
// global_load_lds, amax from LDS, quantize from LDS.
__global__ __launch_bounds__(256) void quant_w_kernel(
    const float* __restrict__ w, unsigned char* __restrict__ qw,
    float* __restrict__ sw)
{
    __shared__ float buf[128 * 128];   // 64 KB
    __shared__ float red[4];

    const int cb = blockIdx.x;   // din block 0..15
    const int rb = blockIdx.y;   // dout block 0..15
    const int e  = blockIdx.z;   // expert 0..7
    const int t  = threadIdx.x;
    const int lane = t & 63, wv = t >> 6;

    const size_t base = ((size_t)e * DOUT + rb * GSZ) * DIN + cb * GSZ;
    const float* wp = w + base;

    // stage 64 KB: 4 waves x 16 iters x 1 KB. 32 sixteen-byte chunks per row.
    #pragma unroll
    for (int j = 0; j < 16; ++j) {
        int f16 = (wv * 16 + j) * 64 + lane;     // 16-byte chunk index 0..4095
        int row = f16 >> 5, cc = f16 & 31;
        async16(buf + (wv * 16 + j) * 256,
                wp + (size_t)row * DIN + cc * 4);
    }
    __syncthreads();

    float a = 0.f;
    #pragma unroll
    for (int i = 0; i < 16; ++i) {
        f32x4 v = *(const f32x4*)(buf + (t + i * 256) * 4);
        a = fmaxf(a, fmaxf(fmaxf(fabsf(v[0]), fabsf(v[1])),
                           fmaxf(fabsf(v[2]), fabsf(v[3]))));
    }
    #pragma unroll
    for (int o = 32; o; o >>= 1) a = fmaxf(a, __shfl_xor(a, o));
    if (lane == 0) red[wv] = a;
    __syncthreads();
    a = fmaxf(fmaxf(red[0], red[1]), fmaxf(red[2], red[3]));
    const float scale = fmaxf(a, EPSQ) / FP8_MAX;
    if (t == 0) sw[(e * 16 + rb) * 16 + cb] = scale;

    unsigned int* qout = (unsigned int*)(qw + base);
    #pragma unroll
    for (int i = 0; i < 16; ++i) {
        int idx = t + i * 256;
        f32x4 v = *(const f32x4*)(buf + idx * 4);
        float q0 = fminf(fmaxf(v[0] / scale, -FP8_MAX), FP8_MAX);
        float q1 = fminf(fmaxf(v[1] / scale, -FP8_MAX), FP8_MAX);
        float q2 = fminf(fmaxf(v[2] / scale, -FP8_MAX), FP8_MAX);
        float q3 = fminf(fmaxf(v[3] / scale, -FP8_MAX), FP8_MAX);
        int lo = __builtin_amdgcn_cvt_pk_fp8_f32(q0, q1, 0, false);
        int pk = __builtin_amdgcn_cvt_pk_fp8_f32(q2, q3, lo, true);
        int r = idx >> 5, c4 = idx & 31;
        qout[r * (DIN / 4) + c4] = (unsigned int)pk;
    }
}

// ---------------------------------------------------------------------------
// Kernel 3: grouped fp8 GEMM, 256x128 tile (BMxBN), 8 waves (4M x 2N, each
// wave 64x64 out), round-2's winning single-buffered 2-barrier K-loop,
// MX-scaled MFMA 32x32x64 fp8 (unit e8m0 scales).
// vs round-2 (128x128): -25% staging traffic through L2/L3 (qx x16 + qw x4
// = 384 MB vs 512 MB) at the SAME 16 waves/CU occupancy:
// LDS = A 32K + B 16K + RsC 16K = 64 KB exactly -> 2 blocks/CU; grid 512 = 2/CU.
//
// Telescoped per-128-k-block rescale with COMBINED row x col table (BN=128
// spans a single weight-scale column, so sw-ratio is block-uniform and is
// folded into RsC):
//   c[s,j] = sx[s,j] * sw[e,nb,j]
//   A_j = A_{j-1} * RsC[j][s] + P_j ;  out = A_15 * RsC[0][s]
//   RsC[j][s] = c[s,j-1]/c[s,j]  (j>0),  RsC[0][s] = c[s,15]
// LDS tiles XOR-swizzled on 16B chunks (pos = chunk ^ (row&7)); a lane's 32B
// fragment = two ds_read_b128 at chunk c = ks*4 + (lane>>5)*2 + {0,1}.
// 32x32 C/D layout: col = lane&31, row = (reg&3) + 8*(reg>>2) + 4*(lane>>5).
// A/B fragment: row = lane&31, k = (lane>>5)*32 + byte.
__global__ __launch_bounds__(512, 4) void gemm_kernel(
    const unsigned char* __restrict__ qx, const float* __restrict__ sx,
    const unsigned char* __restrict__ qw, const float* __restrict__ sw,
    const int* __restrict__ tpe, float* __restrict__ out)
{
    __shared__ __align__(16) unsigned char Asm[256 * 128];  // 32 KB
    __shared__ __align__(16) unsigned char Bsm[128 * 128];  // 16 KB
    __shared__ __align__(16) float RsC[16 * 256];           // 16 KB [kb][row]

    const int tid  = threadIdx.x;
    const int lane = tid & 63;
    const int wv   = tid >> 6;          // 0..7
    const int wm   = wv >> 1;           // 0..3  (M quarter: 64 rows)
    const int wn   = wv & 1;            // 0..1  (N half: 64 cols)
    const int l31  = lane & 31;
    const int h    = lane >> 5;
    const int nb   = blockIdx.x;        // 0..15 (128-col block)
    const int mb   = blockIdx.y;        // 0..31 (256-row block)
    const int r0   = mb * 256, n0 = nb * 128;

    int e = -1, start = 0;
    #pragma unroll
    for (int i = 0; i < NE; ++i) {
        int end = start + tpe[i];
        if (r0 >= start && r0 < end) e = i;
        start = end;
    }
    if (e < 0) {
        f32x4 z = {0.f, 0.f, 0.f, 0.f};
        for (int i = tid; i < 256 * 32; i += 512) {
            int r = i >> 5, c4 = i & 31;
            *(f32x4*)(out + (size_t)(r0 + r) * DOUT + n0 + c4 * 4) = z;
        }
        return;
    }

    // ---- prologue: combined c = sx*sw into Asm scratch, ratios into RsC ----
    {
        float* Cs = (float*)Asm;              // 16 KB scratch inside A tile
        const float* sp  = sx + (size_t)r0 * 16;
        const float* swp = sw + (e * 16 + nb) * 16;
        for (int i = tid; i < 4096; i += 512) {
            int row = i >> 4, kb = i & 15;    // i == row*16 + kb
            Cs[kb * 256 + row] = sp[i] * swp[kb];
        }
        __syncthreads();
        float rv[8];
        #pragma unroll
        for (int j = 0; j < 8; ++j) {
            int i = tid + j * 512;
            int kb = i >> 8, row = i & 255;
            rv[j] = (kb == 0) ? Cs[15 * 256 + row]
                              : Cs[(kb - 1) * 256 + row] / Cs[kb * 256 + row];
        }
        #pragma unroll
        for (int j = 0; j < 8; ++j) RsC[tid + j * 512] = rv[j];
        // loop-top __syncthreads() orders: Cs reads done before Asm staging,
        // RsC writes visible before first rescale use (kb=1).
    }

    const unsigned char* Ag = qx + (size_t)r0 * DIN;
    const unsigned char* Bg = qw + (size_t)e * DOUT * DIN + (size_t)n0 * DIN;

    // staging source indices (per-lane, loop-invariant)
    // A: wave stages 4 KB (rows wv*32..): j=0..3 ; B: 2 KB: j=0..1
    int sa_off[4], sa_dst[4], sb_off[2], sb_dst[2];
    #pragma unroll
    for (int j = 0; j < 4; ++j) {
        int f = wv * 4096 + j * 1024 + lane * 16;   // byte index in 32 KB tile
        int row = f >> 7, pc = (f >> 4) & 7;
        sa_off[j] = row * DIN + ((pc ^ (row & 7)) * 16);
        sa_dst[j] = wv * 4096 + j * 1024;
    }
    #pragma unroll
    for (int j = 0; j < 2; ++j) {
        int f = wv * 2048 + j * 1024 + lane * 16;   // byte index in 16 KB tile
        int row = f >> 7, pc = (f >> 4) & 7;
        sb_off[j] = row * DIN + ((pc ^ (row & 7)) * 16);
        sb_dst[j] = wv * 2048 + j * 1024;
    }

    // fragment read bases (A row = wm*64+mi*32+l31, B row = wn*64+ni*32+l31)
    int abase[2], ax8[2], bbase[2], bx8[2];
    #pragma unroll
    for (int i = 0; i < 2; ++i) {
        int ra = wm * 64 + i * 32 + l31;
        abase[i] = ra * 128; ax8[i] = ra & 7;
        int rb = wn * 64 + i * 32 + l31;
        bbase[i] = rb * 128; bx8[i] = rb & 7;
    }

    f32x16 acc[2][2];
    #pragma unroll
    for (int mi = 0; mi < 2; ++mi)
        #pragma unroll
        for (int ni = 0; ni < 2; ++ni)
            #pragma unroll
            for (int q = 0; q < 16; ++q) acc[mi][ni][q] = 0.f;

    for (int kb = 0; kb < 16; ++kb) {
        __syncthreads();
        #pragma unroll
        for (int j = 0; j < 4; ++j)
            async16(Asm + sa_dst[j], Ag + (size_t)sa_off[j] + kb * GSZ);
        #pragma unroll
        for (int j = 0; j < 2; ++j)
            async16(Bsm + sb_dst[j], Bg + (size_t)sb_off[j] + kb * GSZ);
        __syncthreads();

        if (kb) {   // rescale accumulators into this k-block's units
            #pragma unroll
            for (int mi = 0; mi < 2; ++mi) {
                const float* rp = RsC + kb * 256 + wm * 64 + mi * 32 + 4 * h;
                f32x4 rr[4];
                #pragma unroll
                for (int g = 0; g < 4; ++g) rr[g] = *(const f32x4*)(rp + 8 * g);
                #pragma unroll
                for (int ni = 0; ni < 2; ++ni)
                    #pragma unroll
                    for (int g = 0; g < 4; ++g)
                        #pragma unroll
                        for (int j = 0; j < 4; ++j)
                            acc[mi][ni][g * 4 + j] *= rr[g][j];
            }
        }

        #pragma unroll
        for (int ks = 0; ks < 2; ++ks) {
            const int c0 = ks * 4 + h * 2;
            i32x8 Bk[2];
            #pragma unroll
            for (int ni = 0; ni < 2; ++ni) {
                i32x4 lo = *(const i32x4*)(Bsm + bbase[ni] + (((c0    ) ^ bx8[ni]) * 16));
                i32x4 hi = *(const i32x4*)(Bsm + bbase[ni] + (((c0 + 1) ^ bx8[ni]) * 16));
                #pragma unroll
                for (int q = 0; q < 4; ++q) { Bk[ni][q] = lo[q]; Bk[ni][q + 4] = hi[q]; }
            }
            #pragma unroll
            for (int mi = 0; mi < 2; ++mi) {
                i32x8 Af;
                i32x4 alo = *(const i32x4*)(Asm + abase[mi] + (((c0    ) ^ ax8[mi]) * 16));
                i32x4 ahi = *(const i32x4*)(Asm + abase[mi] + (((c0 + 1) ^ ax8[mi]) * 16));
                #pragma unroll
                for (int q = 0; q < 4; ++q) { Af[q] = alo[q]; Af[q + 4] = ahi[q]; }
                #pragma unroll
                for (int ni = 0; ni < 2; ++ni)
                    acc[mi][ni] = __builtin_amdgcn_mfma_scale_f32_32x32x64_f8f6f4(
                        Af, Bk[ni], acc[mi][ni],
                        0, 0,                       // cbsz=fp8, blgp=fp8
                        0, 0x7f7f7f7f,              // A scale: e8m0 1.0
                        0, 0x7f7f7f7f);             // B scale: e8m0 1.0
            }
        }
    }

    // epilogue: apply final scale (RsC kb=0 slot).
    // C/D: col = l31, row = (reg&3) + 8*(reg>>2) + 4*h
    #pragma unroll
    for (int mi = 0; mi < 2; ++mi) {
        const float* fp = RsC + wm * 64 + mi * 32 + 4 * h;
        f32x4 fv[4];
        #pragma unroll
        for (int g = 0; g < 4; ++g) fv[g] = *(const f32x4*)(fp + 8 * g);
        const int rbase = r0 + wm * 64 + mi * 32 + 4 * h;
        #pragma unroll
        for (int ni = 0; ni < 2; ++ni) {
            const int col = n0 + wn * 64 + ni * 32 + l31;
            #pragma unroll
            for (int g = 0; g < 4; ++g)
                #pragma unroll
                for (int j = 0; j < 4; ++j)
                    out[(size_t)(rbase + 8 * g + j) * DOUT + col] =
                        acc[mi][ni][g * 4 + j] * fv[g][j];
        }
    }
}

// ---------------------------------------------------------------------------
extern "C" void kernel_launch(void* const* d_in, const int* in_sizes, int n_in,
                              void* d_out, int out_size, void* d_ws, size_t ws_size,
                              hipStream_t stream) {
    const float* x   = (const float*)d_in[0];   // [8192, 2048] fp32
    const float* wt  = (const float*)d_in[1];   // [16384, 2048] fp32
    const int*   tpe = (const int*)d_in[2];     // [8]
    float* out = (float*)d_out;                 // [8192, 2048] fp32

    char* ws = (char*)d_ws;
    unsigned char* qx = (unsigned char*)ws;                       // 16 MB
    unsigned char* qw = qx + (size_t)SEQ * DIN;                   // 32 MB
    float* sx = (float*)(qw + (size_t)NE * DOUT * DIN);           // 512 KB
    float* sw = sx + (size_t)SEQ * 16;                            // 4 KB

    quant_x_kernel<<<SEQ * DIN / 4 / 256, 256, 0, stream>>>(x, qx, sx);
    quant_w_kernel<<<dim3(16, 16, NE), 256, 0, stream>>>(wt, qw, sw);
    gemm_kernel<<<dim3(DOUT / 128, SEQ / 256), 512, 0, stream>>>(
        qx, sx, qw, sw, tpe, out);
}